// Round 1
// baseline (417.812 us; speedup 1.0000x reference)
//
#include <hip/hip_runtime.h>
#include <math.h>

#define NQ   64
#define DIM  256
#define SEQ  128
#define CAP  500000
#define TOPK 5
#define TILE 64
#define NBLK 1024                 // sims kernel grid
#define NCAND (NBLK * TOPK)       // candidates per query = 5120

// ---------------- Kernel A: query mean over S + L2 normalize ----------------
__global__ void qmean_norm_kernel(const float* __restrict__ query,
                                  float* __restrict__ qn) {
    int b = blockIdx.x;        // 64 blocks
    int d = threadIdx.x;       // 256 threads = DIM
    const float* qb = query + (size_t)b * SEQ * DIM;
    float s = 0.f;
    #pragma unroll 4
    for (int t = 0; t < SEQ; ++t) s += qb[(size_t)t * DIM + d];
    float m = s * (1.0f / SEQ);

    float ss = m * m;
    #pragma unroll
    for (int off = 32; off > 0; off >>= 1) ss += __shfl_down(ss, off, 64);
    __shared__ float red[4];
    if ((threadIdx.x & 63) == 0) red[threadIdx.x >> 6] = ss;
    __syncthreads();
    float tot = red[0] + red[1] + red[2] + red[3];
    float r = 1.0f / fmaxf(sqrtf(tot), 1e-12f);
    qn[b * DIM + d] = m * r;
}

// ---------------- Kernel D: counts passthrough (out poisoned each run) ------
__global__ void copy_counts_kernel(const float* __restrict__ ac,
                                   float* __restrict__ outCnt) {
    int i = blockIdx.x * blockDim.x + threadIdx.x;
    if (i < CAP / 4) ((float4*)outCnt)[i] = ((const float4*)ac)[i];
}

// ---------------- Kernel B: sims + per-block top-5 candidates ---------------
// block = 256 threads (4 waves). Tile = 64 keys.
// Compute phase: lane = key-offset, wave handles 16 queries. Key row via
// per-lane float4; q via wave-uniform (scalar) loads. Key-norm folded in.
// Update phase: lane = query, wave scans its 16 key-offsets from padded LDS.
__global__ __launch_bounds__(256) void sims_topk_kernel(
        const float* __restrict__ keys, const float* __restrict__ qn,
        float* __restrict__ candV, int* __restrict__ candI) {
    __shared__ float smem[64 * 65];   // sims tile [q][key+pad]; reused for merge
    const int lane = threadIdx.x & 63;
    const int wave = threadIdx.x >> 6;
    const int qb = __builtin_amdgcn_readfirstlane(wave << 4);  // wave-scalar

    float tv[TOPK]; int ti[TOPK];
    #pragma unroll
    for (int p = 0; p < TOPK; ++p) { tv[p] = -INFINITY; ti[p] = 0; }

    const int NT = (CAP + TILE - 1) / TILE;   // 7813
    for (int t = blockIdx.x; t < NT; t += gridDim.x) {
        const int kb = t * TILE;
        const int kid = kb + lane;
        const bool valid = (kid < CAP);
        const float4* __restrict__ krow =
            (const float4*)(keys + (size_t)(valid ? kid : 0) * DIM);
        const float4* __restrict__ qrow = (const float4*)(qn + qb * DIM);

        float acc[16];
        #pragma unroll
        for (int j = 0; j < 16; ++j) acc[j] = 0.f;
        float kss = 0.f;

        for (int c = 0; c < DIM / 4; ++c) {
            float4 k4 = krow[c];
            kss = fmaf(k4.x, k4.x, fmaf(k4.y, k4.y,
                  fmaf(k4.z, k4.z, fmaf(k4.w, k4.w, kss))));
            #pragma unroll
            for (int j = 0; j < 16; ++j) {
                float4 q4 = qrow[j * (DIM / 4) + c];   // uniform -> scalar load
                acc[j] = fmaf(k4.x, q4.x, fmaf(k4.y, q4.y,
                         fmaf(k4.z, q4.z, fmaf(k4.w, q4.w, acc[j]))));
            }
        }
        float rk = 1.0f / fmaxf(sqrtf(kss), 1e-12f);
        #pragma unroll
        for (int j = 0; j < 16; ++j)
            smem[(qb + j) * 65 + lane] = valid ? acc[j] * rk : -INFINITY;
        __syncthreads();

        // update: lane = query; this wave scans key-offsets [16*wave, 16*wave+16)
        #pragma unroll
        for (int ks = 0; ks < 16; ++ks) {
            const int ko = (wave << 4) + ks;
            float v = smem[lane * 65 + ko];
            if (v > tv[TOPK - 1]) {
                tv[4] = v; ti[4] = kb + ko;
                #pragma unroll
                for (int p = 4; p > 0; --p) {
                    if (tv[p] > tv[p - 1]) {
                        float fv = tv[p]; tv[p] = tv[p - 1]; tv[p - 1] = fv;
                        int  fi = ti[p]; ti[p] = ti[p - 1]; ti[p - 1] = fi;
                    }
                }
            }
        }
        __syncthreads();
    }

    // dump per-wave lists to LDS, wave0 merges -> 5 candidates per query
    #pragma unroll
    for (int p = 0; p < TOPK; ++p) {
        smem[wave * 320 + lane * 5 + p] = tv[p];
        ((int*)smem)[2048 + wave * 320 + lane * 5 + p] = ti[p];
    }
    __syncthreads();
    if (wave == 0) {
        float fv[TOPK]; int fi[TOPK];
        #pragma unroll
        for (int p = 0; p < TOPK; ++p) { fv[p] = -INFINITY; fi[p] = 0; }
        for (int w = 0; w < 4; ++w) {
            #pragma unroll
            for (int p = 0; p < TOPK; ++p) {
                float v = smem[w * 320 + lane * 5 + p];
                int  id = ((int*)smem)[2048 + w * 320 + lane * 5 + p];
                if (v > fv[TOPK - 1]) {
                    fv[4] = v; fi[4] = id;
                    #pragma unroll
                    for (int pp = 4; pp > 0; --pp) {
                        if (fv[pp] > fv[pp - 1]) {
                            float a = fv[pp]; fv[pp] = fv[pp - 1]; fv[pp - 1] = a;
                            int   c = fi[pp]; fi[pp] = fi[pp - 1]; fi[pp - 1] = c;
                        }
                    }
                }
            }
        }
        // layout: candV[(q * gridDim.x + block) * 5 + p] -> per-query contiguous
        size_t base = ((size_t)lane * gridDim.x + blockIdx.x) * TOPK;
        #pragma unroll
        for (int p = 0; p < TOPK; ++p) { candV[base + p] = fv[p]; candI[base + p] = fi[p]; }
    }
}

// ---------------- Kernel C: global merge + gather + scatter ------------------
__global__ void finalize_kernel(const float* __restrict__ candV,
                                const int* __restrict__ candI,
                                const float* __restrict__ values,
                                float* __restrict__ outRet,
                                float* __restrict__ outCnt) {
    const int b = blockIdx.x;    // 64 blocks = queries
    const int t = threadIdx.x;   // 256
    __shared__ float rv[256];
    __shared__ int   rp[256];
    __shared__ int   chosen[TOPK];
    __shared__ int   kidx[TOPK];
    const float* cv = candV + (size_t)b * NCAND;

    for (int pass = 0; pass < TOPK; ++pass) {
        float lv = -INFINITY; int lp = 0x7fffffff;
        for (int m = t; m < NCAND; m += 256) {
            bool skip = false;
            for (int k = 0; k < pass; ++k) skip |= (m == chosen[k]);
            float v = cv[m];
            if (!skip && (v > lv || (v == lv && m < lp))) { lv = v; lp = m; }
        }
        rv[t] = lv; rp[t] = lp;
        __syncthreads();
        for (int s = 128; s > 0; s >>= 1) {
            if (t < s) {
                if (rv[t + s] > rv[t] || (rv[t + s] == rv[t] && rp[t + s] < rp[t])) {
                    rv[t] = rv[t + s]; rp[t] = rp[t + s];
                }
            }
            __syncthreads();
        }
        if (t == 0) chosen[pass] = rp[0];
        __syncthreads();
    }
    if (t < TOPK) kidx[t] = candI[(size_t)b * NCAND + chosen[t]];
    __syncthreads();

    float s = 0.f;
    #pragma unroll
    for (int p = 0; p < TOPK; ++p) s += values[(size_t)kidx[p] * DIM + t];
    outRet[b * DIM + t] = s * 0.2f;

    if (t < TOPK) atomicAdd(&outCnt[kidx[t]], 1.0f);
}

// ---------------- launch -----------------------------------------------------
extern "C" void kernel_launch(void* const* d_in, const int* in_sizes, int n_in,
                              void* d_out, int out_size, void* d_ws, size_t ws_size,
                              hipStream_t stream) {
    const float* query  = (const float*)d_in[0];
    const float* keys   = (const float*)d_in[1];
    const float* values = (const float*)d_in[2];
    const float* acnt   = (const float*)d_in[3];
    float* outRet = (float*)d_out;
    float* outCnt = outRet + NQ * DIM;

    char* ws = (char*)d_ws;
    float* qn    = (float*)ws;                                        // 64 KB
    float* candV = (float*)(ws + 65536);                              // 1.25 MB
    int*   candI = (int*)(ws + 65536 + (size_t)NQ * NCAND * 4);       // 1.25 MB

    qmean_norm_kernel<<<NQ, 256, 0, stream>>>(query, qn);
    copy_counts_kernel<<<(CAP / 4 + 255) / 256, 256, 0, stream>>>(acnt, outCnt);
    sims_topk_kernel<<<NBLK, 256, 0, stream>>>(keys, qn, candV, candI);
    finalize_kernel<<<NQ, 256, 0, stream>>>(candV, candI, values, outRet, outCnt);
}

// Round 2
// 208.377 us; speedup vs baseline: 2.0051x; 2.0051x over previous
//
#include <hip/hip_runtime.h>
#include <math.h>

#define NQ    64
#define DIM   256
#define SEQ   128
#define CAP   500000
#define TOPK  5
#define KT    32                 // keys per tile
#define NTILE (CAP / KT)         // 15625 exact
#define NBLK  768                // 3 blocks/CU * 256 CU
#define PB    8                  // per-block per-query candidates
#define NC    (NBLK * PB)        // 6144 candidates per query
#define DELTA 2.0e-3f            // bf16-sim safety margin (~20 sigma)
#define MAXC  192

typedef short short8v __attribute__((ext_vector_type(8)));
typedef float f32x4   __attribute__((ext_vector_type(4)));

__device__ inline unsigned pkbf(float a, float b) {   // 2x fp32 -> packed bf16 (RNE)
    unsigned ua = __builtin_bit_cast(unsigned, a);
    unsigned ub = __builtin_bit_cast(unsigned, b);
    ua = (ua + 0x7fffu + ((ua >> 16) & 1u)) >> 16;
    ub = (ub + 0x7fffu + ((ub >> 16) & 1u)) >> 16;
    return ua | (ub << 16);
}

// ---------------- Kernel A: query mean over S + L2 normalize ----------------
__global__ void qmean_norm_kernel(const float* __restrict__ query,
                                  float* __restrict__ qn) {
    int b = blockIdx.x;
    int d = threadIdx.x;
    const float* qb = query + (size_t)b * SEQ * DIM;
    float s = 0.f;
    #pragma unroll 4
    for (int t = 0; t < SEQ; ++t) s += qb[(size_t)t * DIM + d];
    float m = s * (1.0f / SEQ);
    float ss = m * m;
    #pragma unroll
    for (int off = 32; off > 0; off >>= 1) ss += __shfl_down(ss, off, 64);
    __shared__ float red[4];
    if ((threadIdx.x & 63) == 0) red[threadIdx.x >> 6] = ss;
    __syncthreads();
    float tot = red[0] + red[1] + red[2] + red[3];
    float r = 1.0f / fmaxf(sqrtf(tot), 1e-12f);
    qn[b * DIM + d] = m * r;
}

// ---------------- counts passthrough (d_out poisoned each run) ---------------
__global__ void copy_counts_kernel(const float* __restrict__ ac,
                                   float* __restrict__ outCnt) {
    int i = blockIdx.x * blockDim.x + threadIdx.x;
    if (i < CAP / 4) ((float4*)outCnt)[i] = ((const float4*)ac)[i];
}

// ---------------- Kernel B: bf16-MFMA sims + per-block top-8 ----------------
// 256 thr (4 waves). Tile = 32 keys. Double-buffered swizzled bf16 LDS tile.
// Wave w owns q-tile [16w,16w+16); MFMA 16x16x32 over 2 key-subtiles x 8 K-steps.
__global__ __launch_bounds__(256, 3) void sims_mfma_topk(
        const float* __restrict__ keys, const float* __restrict__ qn,
        float* __restrict__ candV, int* __restrict__ candI) {
    __shared__ __align__(16) unsigned short kb[2][KT * DIM];  // 2 x 16 KB, swizzled
    __shared__ float sims[64][33];                            // 8448 B
    __shared__ float pss[KT][8];                              // fp32 ssq partials
    __shared__ float kssr[KT];                                // rsqrt(|k|^2)

    const int tid  = threadIdx.x;
    const int lane = tid & 63;
    const int wave = tid >> 6;
    const int key0 = lane & 15;
    const int g    = lane >> 4;        // k-chunk group 0..3
    const int kl3  = key0 & 7;

    // ---- A fragments: wave's 16 queries, K=256 -> 8 steps, bf16 in regs ----
    short8v afr[8];
    {
        const float* qrow = qn + ((wave << 4) + key0) * DIM;
        int kbase = g * 8;
        #pragma unroll
        for (int st = 0; st < 8; ++st) {
            float4 a = *(const float4*)(qrow + st * 32 + kbase);
            float4 b = *(const float4*)(qrow + st * 32 + kbase + 4);
            uint4 w;
            w.x = pkbf(a.x, a.y); w.y = pkbf(a.z, a.w);
            w.z = pkbf(b.x, b.y); w.w = pkbf(b.z, b.w);
            afr[st] = __builtin_bit_cast(short8v, w);
        }
    }

    float tv[PB]; int ti[PB];
    #pragma unroll
    for (int p = 0; p < PB; ++p) { tv[p] = -INFINITY; ti[p] = 0; }

    // staging: thread -> row r = tid>>3, eighth e = tid&7 (32 contig floats)
    const int srow = tid >> 3, se = tid & 7;
    float4 stg[8];
    auto issue_loads = [&](int tile) {
        const float* src = keys + (size_t)tile * KT * DIM + srow * DIM + se * 32;
        #pragma unroll
        for (int j = 0; j < 8; ++j) stg[j] = ((const float4*)src)[j];
    };
    auto write_stage = [&](int buf) {
        float ssq = 0.f; unsigned u[16];
        #pragma unroll
        for (int j = 0; j < 8; ++j) {
            float4 v = stg[j];
            ssq += v.x * v.x + v.y * v.y + v.z * v.z + v.w * v.w;
            u[2 * j]     = pkbf(v.x, v.y);
            u[2 * j + 1] = pkbf(v.z, v.w);
        }
        char* kc = (char*)&kb[buf][0];
        unsigned base = srow * 512;
        #pragma unroll
        for (int c = 0; c < 4; ++c) {
            unsigned Xs = ((unsigned)(se * 64 + c * 16)) ^ ((srow & 7) << 4);
            uint4 w; w.x = u[4*c]; w.y = u[4*c+1]; w.z = u[4*c+2]; w.w = u[4*c+3];
            *(uint4*)(kc + base + Xs) = w;
        }
        pss[srow][se] = ssq;
    };

    // prologue: stage first tile
    int tile = blockIdx.x;
    issue_loads(tile);
    write_stage(0);
    __syncthreads();

    int it = 0;
    while (tile < NTILE) {
        const int ntile = tile + NBLK;
        const bool has_next = (ntile < NTILE);
        if (has_next) issue_loads(ntile);

        if (tid < KT) {   // key-norm reduce (reads pss of current tile)
            float s = 0.f;
            #pragma unroll
            for (int j = 0; j < 8; ++j) s += pss[tid][j];
            kssr[tid] = rsqrtf(fmaxf(s, 1e-24f));
        }

        const int cur = it & 1;
        f32x4 acc0 = {0.f, 0.f, 0.f, 0.f}, acc1 = {0.f, 0.f, 0.f, 0.f};
        const char* kc = (const char*)&kb[cur][0];
        #pragma unroll
        for (int st = 0; st < 8; ++st) {
            unsigned Xs = ((unsigned)(st * 64 + g * 16)) ^ (kl3 << 4);
            short8v b0 = *(const short8v*)(kc + key0 * 512 + Xs);
            short8v b1 = *(const short8v*)(kc + key0 * 512 + 8192 + Xs);
            acc0 = __builtin_amdgcn_mfma_f32_16x16x32_bf16(afr[st], b0, acc0, 0, 0, 0);
            acc1 = __builtin_amdgcn_mfma_f32_16x16x32_bf16(afr[st], b1, acc1, 0, 0, 0);
        }
        __syncthreads();   // kssr ready; kb[cur]/pss consumed

        // scale by key norm, write sims tile (D: row=(l>>4)*4+r, col=l&15)
        {
            float rk0 = kssr[key0], rk1 = kssr[16 + key0];
            int q0 = (wave << 4) + (g << 2);
            #pragma unroll
            for (int r = 0; r < 4; ++r) {
                sims[q0 + r][key0]      = acc0[r] * rk0;
                sims[q0 + r][16 + key0] = acc1[r] * rk1;
            }
        }
        if (has_next) write_stage(cur ^ 1);
        __syncthreads();   // sims ready; next buffer staged

        // top-8 update: lane = query, wave scans its 8 key slots
        #pragma unroll
        for (int ks = 0; ks < 8; ++ks) {
            int ko = (wave << 3) + ks;
            float v = sims[lane][ko];
            if (v > tv[PB - 1]) {
                tv[PB - 1] = v; ti[PB - 1] = tile * KT + ko;
                #pragma unroll
                for (int p = PB - 1; p > 0; --p) {
                    if (tv[p] > tv[p - 1]) {
                        float fv = tv[p]; tv[p] = tv[p - 1]; tv[p - 1] = fv;
                        int   fi = ti[p]; ti[p] = ti[p - 1]; ti[p - 1] = fi;
                    }
                }
            }
        }
        tile = ntile; ++it;
    }

    // ---- per-block merge: 4 wave-lists of 8 -> top-8 per query ----
    float* mv = (float*)&kb[0][0];
    int*   mi = (int*)&kb[0][0] + 2048;
    {
        int base = (wave * 64 + lane) * PB;
        #pragma unroll
        for (int p = 0; p < PB; ++p) { mv[base + p] = tv[p]; mi[base + p] = ti[p]; }
    }
    __syncthreads();
    if (wave == 0) {
        float fv[PB]; int fi[PB];
        #pragma unroll
        for (int p = 0; p < PB; ++p) { fv[p] = -INFINITY; fi[p] = 0; }
        for (int w = 0; w < 4; ++w) {
            #pragma unroll
            for (int p = 0; p < PB; ++p) {
                float v = mv[(w * 64 + lane) * PB + p];
                int  id = mi[(w * 64 + lane) * PB + p];
                if (v > fv[PB - 1]) {
                    fv[PB - 1] = v; fi[PB - 1] = id;
                    #pragma unroll
                    for (int p2 = PB - 1; p2 > 0; --p2) {
                        if (fv[p2] > fv[p2 - 1]) {
                            float a = fv[p2]; fv[p2] = fv[p2 - 1]; fv[p2 - 1] = a;
                            int   c = fi[p2]; fi[p2] = fi[p2 - 1]; fi[p2 - 1] = c;
                        }
                    }
                }
            }
        }
        size_t cb = ((size_t)lane * NBLK + blockIdx.x) * PB;
        #pragma unroll
        for (int p = 0; p < PB; ++p) { candV[cb + p] = fv[p]; candI[cb + p] = fi[p]; }
    }
}

// ---- Kernel C: global bf16-top5 -> threshold select -> exact fp32 rescore ----
__global__ void finalize_kernel(const float* __restrict__ candV,
                                const int* __restrict__ candI,
                                const float* __restrict__ keys,
                                const float* __restrict__ qn,
                                const float* __restrict__ values,
                                float* __restrict__ outRet,
                                float* __restrict__ outCnt) {
    const int b = blockIdx.x;      // query
    const int t = threadIdx.x;     // 256
    const int lane = t & 63, wave = t >> 6;
    __shared__ float rv[256]; __shared__ int rp[256];
    __shared__ int   chosen[TOPK];
    __shared__ float v5s;
    __shared__ int   clist[MAXC];
    __shared__ float rsc[MAXC];
    __shared__ int   ccnt;
    __shared__ float qs[DIM];
    __shared__ int   kidx[TOPK];

    const float* cv = candV + (size_t)b * NC;
    const int*   ci = candI + (size_t)b * NC;

    // phase 1: 5 argmax passes over bf16-sims -> v5 (5th largest)
    for (int pass = 0; pass < TOPK; ++pass) {
        float lv = -INFINITY; int lp = 0x7fffffff;
        for (int m = t; m < NC; m += 256) {
            bool skip = false;
            for (int k2 = 0; k2 < pass; ++k2) skip |= (m == chosen[k2]);
            float v = cv[m];
            if (!skip && (v > lv || (v == lv && m < lp))) { lv = v; lp = m; }
        }
        rv[t] = lv; rp[t] = lp;
        __syncthreads();
        for (int s = 128; s > 0; s >>= 1) {
            if (t < s) {
                if (rv[t + s] > rv[t] || (rv[t + s] == rv[t] && rp[t + s] < rp[t])) {
                    rv[t] = rv[t + s]; rp[t] = rp[t + s];
                }
            }
            __syncthreads();
        }
        if (t == 0) { chosen[pass] = rp[0]; if (pass == TOPK - 1) v5s = rv[0]; }
        __syncthreads();
    }

    // phase 2: collect candidates >= v5 - DELTA (provable superset of true top5)
    if (t == 0) ccnt = 0;
    __syncthreads();
    float thr = v5s - DELTA;
    for (int m = t; m < NC; m += 256) {
        if (cv[m] >= thr) {
            int pos = atomicAdd(&ccnt, 1);
            if (pos < MAXC) clist[pos] = ci[m];
        }
    }
    qs[t] = qn[b * DIM + t];
    __syncthreads();
    int cnt = min(ccnt, MAXC);

    // phase 3: exact fp32 rescore (one wave per candidate)
    for (int c = wave; c < cnt; c += 4) {
        const float4 k4 = *(const float4*)(keys + (size_t)clist[c] * DIM + lane * 4);
        const float4 q4 = *(const float4*)(qs + lane * 4);
        float d  = q4.x * k4.x + q4.y * k4.y + q4.z * k4.z + q4.w * k4.w;
        float s2 = k4.x * k4.x + k4.y * k4.y + k4.z * k4.z + k4.w * k4.w;
        #pragma unroll
        for (int off = 1; off < 64; off <<= 1) {
            d  += __shfl_xor(d, off, 64);
            s2 += __shfl_xor(s2, off, 64);
        }
        if (lane == 0) rsc[c] = d * rsqrtf(fmaxf(s2, 1e-24f));
    }
    __syncthreads();

    // phase 4: exact top-5 among rescored candidates
    for (int pass = 0; pass < TOPK; ++pass) {
        float lv = -INFINITY; int lp = 0x7fffffff;
        if (t < cnt) {
            bool skip = false;
            for (int k2 = 0; k2 < pass; ++k2) skip |= (t == chosen[k2]);
            if (!skip) { lv = rsc[t]; lp = t; }
        }
        rv[t] = lv; rp[t] = lp;
        __syncthreads();
        for (int s = 128; s > 0; s >>= 1) {
            if (t < s) {
                if (rv[t + s] > rv[t] || (rv[t + s] == rv[t] && rp[t + s] < rp[t])) {
                    rv[t] = rv[t + s]; rp[t] = rp[t + s];
                }
            }
            __syncthreads();
        }
        if (t == 0) { chosen[pass] = rp[0]; kidx[pass] = clist[rp[0]]; }
        __syncthreads();
    }

    // phase 5: gather values + mean; scatter counts
    float s = 0.f;
    #pragma unroll
    for (int p = 0; p < TOPK; ++p) s += values[(size_t)kidx[p] * DIM + t];
    outRet[b * DIM + t] = s * 0.2f;
    if (t < TOPK) atomicAdd(&outCnt[kidx[t]], 1.0f);
}

// ---------------- launch -----------------------------------------------------
extern "C" void kernel_launch(void* const* d_in, const int* in_sizes, int n_in,
                              void* d_out, int out_size, void* d_ws, size_t ws_size,
                              hipStream_t stream) {
    const float* query  = (const float*)d_in[0];
    const float* keys   = (const float*)d_in[1];
    const float* values = (const float*)d_in[2];
    const float* acnt   = (const float*)d_in[3];
    float* outRet = (float*)d_out;
    float* outCnt = outRet + NQ * DIM;

    char* ws = (char*)d_ws;
    float* qn    = (float*)ws;                                       // 64 KB
    float* candV = (float*)(ws + 65536);                             // 1.5 MB
    int*   candI = (int*)(ws + 65536 + (size_t)NQ * NC * 4);         // 1.5 MB

    qmean_norm_kernel<<<NQ, 256, 0, stream>>>(query, qn);
    copy_counts_kernel<<<(CAP / 4 + 255) / 256, 256, 0, stream>>>(acnt, outCnt);
    sims_mfma_topk<<<NBLK, 256, 0, stream>>>(keys, qn, candV, candI);
    finalize_kernel<<<NQ, 256, 0, stream>>>(candV, candI, keys, qn, values,
                                            outRet, outCnt);
}